// Round 4
// baseline (259.482 us; speedup 1.0000x reference)
//
#include <hip/hip_runtime.h>
#include <hip/hip_bf16.h>
#include <cstdint>

// MHD PINN loss, fused + persistent, layer-pipelined wave specialization.
// N=131072 pts, H=256. Swapped-operand: D = W * X^T (m=neuron, n=16pts x 4 streams).
// Block = 512 thr (8 waves), grid = 256 (1 block/CU, 2 waves/SIMD — register-resident
// weights force ~256 regs/wave; occupancy 22% is by design).
// KEY CHANGE vs previous rounds: waves 0-3 own L2 (64 neurons each, wf[4][8]=128 VGPR),
// waves 4-7 own L3. One-tile software pipeline: between one barrier pair, G2 runs
// L2(tile i) while G3 runs L3(tile i-1) on separate LDS buffers.
//   - B-fragment reuse 2 -> 4: LDS reads 576 KB -> 320 KB per tile (LDS-BW was the
//     binding constraint: ~5100 cyc LDS vs ~1270 cyc MFMA per tile before).
//   - L2/L3 MFMA run concurrently (each SIMD hosts one G2 + one G3 wave).
//   - 3 barriers/tile instead of 5.
// Streams: s=0 forward h, s=1..3 tangents d/dx,d/dy,d/dt; X row = s*16+p.

#define LDW 264   // X tile row stride in ushorts (132 words == 4 mod 32 -> 2-way max)
#define TPTS 16
#define GRIDB 256

typedef __attribute__((ext_vector_type(8))) short v8h;   // 8 x bf16
typedef __attribute__((ext_vector_type(4))) float v4f;

__device__ __forceinline__ ushort f2b(float f) {           // fp32 -> bf16 RNE
    uint32_t u = __float_as_uint(f);
    u = (u + 0x7fffu + ((u >> 16) & 1u)) >> 16;
    return (ushort)u;
}
__device__ __forceinline__ uint32_t pk2(float a, float b) { // packed cvt (v_cvt_pk_bf16_f32)
    union { __hip_bfloat162 h2; uint32_t u; } cv;
    cv.h2 = __float22bfloat162_rn(make_float2(a, b));
    return cv.u;
}
__device__ __forceinline__ float fast_tanh(float x) {
    float e = __expf(2.0f * x);
    return 1.0f - 2.0f * __builtin_amdgcn_rcpf(e + 1.0f);
}

// prep: W2,W3 (256x256 [k][n]) -> bf16 transposed Wt[n][k]; W4 (256x6) -> Wt4[16][256] padded
__global__ void prep_weights(const float* __restrict__ W2, const float* __restrict__ W3,
                             const float* __restrict__ W4,
                             ushort* __restrict__ Wt2, ushort* __restrict__ Wt3,
                             ushort* __restrict__ Wt4) {
    int idx = blockIdx.x * 256 + threadIdx.x;
    if (idx < 65536) {
        int k = idx >> 8, n = idx & 255;
        Wt2[n * 256 + k] = f2b(W2[k * 256 + n]);
        Wt3[n * 256 + k] = f2b(W3[k * 256 + n]);
    }
    if (idx < 4096) {
        int n = idx >> 8, k = idx & 255;
        Wt4[n * 256 + k] = (n < 6) ? f2b(W4[k * 6 + n]) : (ushort)0;
    }
}

__global__ __launch_bounds__(512, 2)
void mhd_fused(const float* __restrict__ coords,
               const float* __restrict__ W1, const float* __restrict__ b1,
               const float* __restrict__ b2, const float* __restrict__ b3,
               const float* __restrict__ b4,
               const float* __restrict__ wts,
               const ushort* __restrict__ Wt2, const ushort* __restrict__ Wt3,
               const ushort* __restrict__ Wt4,
               float* __restrict__ out, int npts, float inv_n) {
    __shared__ ushort XsA[64 * LDW];        // L1 output (single buffer)
    __shared__ ushort XsB[2][64 * LDW];     // L2 output (double buffer: pipeline cross-over)
    __shared__ ushort XsC[64 * LDW];        // L3 output (single buffer)
    __shared__ ushort W4s[16 * LDW];
    __shared__ float  cs[TPTS * 3];
    __shared__ float  Y4[4][TPTS][8];

    const int tid  = threadIdx.x;
    const int lane = tid & 63;
    const int wv   = tid >> 6;      // 0..7
    const int q    = lane >> 4;
    const int l15  = lane & 15;
    const int g3   = wv >> 2;       // 0 = L2 group (waves 0-3), 1 = L3 group (waves 4-7)
    const int wvg  = wv & 3;        // index within group

    // ---- stage W4 (16x256, padded) into LDS ----------------------------------
    for (int idx = tid; idx < 16 * 256; idx += 512)
        W4s[(idx >> 8) * LDW + (idx & 255)] = Wt4[idx];

    // ---- weight fragments -> registers: group owns one layer, 64 neurons/wave --
    const ushort* Wsrc = g3 ? Wt3 : Wt2;
    const float*  bsrc = g3 ? b3  : b2;
    v8h wf[4][8];                                   // 128 VGPR
    #pragma unroll
    for (int mt = 0; mt < 4; mt++) {
        const int nrow = (wvg * 64 + mt * 16 + l15) * 256 + q * 8;
        #pragma unroll
        for (int kk = 0; kk < 8; kk++)
            wf[mt][kk] = *(const v8h*)(&Wsrc[nrow + kk * 32]);
    }

    const int jj = tid & 255, ph = tid >> 8;
    const float l1w0 = W1[jj], l1w1 = W1[256 + jj], l1w2 = W1[512 + jj], l1b = b1[jj];

    const int ntiles = (npts + TPTS - 1) / TPTS;
    const int nt_blk = (ntiles > (int)blockIdx.x)
                         ? (ntiles - (int)blockIdx.x + GRIDB - 1) / GRIDB : 0;

    float vsum = 0.0f;

    // prologue: coords for tile 0
    if (tid < TPTS * 3 && nt_blk > 0) {
        int p = tid / 3, c = tid % 3;
        int gp = (int)blockIdx.x * TPTS + p; if (gp >= npts) gp = npts - 1;
        cs[tid] = coords[gp * 3 + c];
    }
    __syncthreads();

    // pipeline: iteration i runs L1(i) | [L2(i) || L3(i-1)] | L4(i-1) | residual(i-1)
    for (int i = 0; i <= nt_blk; ++i) {
        const int base = ((int)blockIdx.x + i * GRIDB) * TPTS;

        // ---- phase 1: layer 1 (3->256) for tile i -> XsA ----------------------
        if (i < nt_blk) {
            #pragma unroll
            for (int pp = 0; pp < 8; pp++) {
                const int p = ph * 8 + pp;
                float x = cs[p * 3], y = cs[p * 3 + 1], t = cs[p * 3 + 2];
                float pre = fmaf(x, l1w0, fmaf(y, l1w1, fmaf(t, l1w2, l1b)));
                float h = fast_tanh(pre);
                float d = 1.0f - h * h;
                XsA[p * LDW + jj]        = f2b(h);
                XsA[(16 + p) * LDW + jj] = f2b(d * l1w0);
                XsA[(32 + p) * LDW + jj] = f2b(d * l1w1);
                XsA[(48 + p) * LDW + jj] = f2b(d * l1w2);
            }
        }
        __syncthreads();   // B_a: XsA(i) ready; XsB[i&1] free (G3 read it last iter)

        // ---- phase 2: G2 = L2(tile i): XsA -> XsB[i&1]
        //               G3 = L3(tile i-1): XsB[(i-1)&1] -> XsC  (concurrent) ------
        {
            const ushort* src = g3 ? XsB[(i + 1) & 1] : XsA;   // (i-1)&1 == (i+1)&1
            ushort*       dst = g3 ? XsC : XsB[i & 1];
            const bool act = g3 ? (i >= 1) : (i < nt_blk);
            if (act) {
                v4f acc[4][4];
                #pragma unroll
                for (int a = 0; a < 4; a++)
                    #pragma unroll
                    for (int b = 0; b < 4; b++) {
                        v4f z = {0.0f, 0.0f, 0.0f, 0.0f};
                        acc[a][b] = z;
                    }
                #pragma unroll
                for (int kk = 0; kk < 8; kk++) {
                    v8h B[4];
                    #pragma unroll
                    for (int nt = 0; nt < 4; nt++)
                        B[nt] = *(const v8h*)(&src[(nt * 16 + l15) * LDW + kk * 32 + q * 8]);
                    #pragma unroll
                    for (int mt = 0; mt < 4; mt++)
                        #pragma unroll
                        for (int nt = 0; nt < 4; nt++)
                            acc[mt][nt] = __builtin_amdgcn_mfma_f32_16x16x32_bf16(
                                              wf[mt][kk], B[nt], acc[mt][nt], 0, 0, 0);
                }
                // D row(neuron) = mt*16 + q*4 + r, col = nt*16 + l15 (s = nt, p = l15)
                #pragma unroll
                for (int mt = 0; mt < 4; mt++) {
                    const int nb = wvg * 64 + mt * 16 + q * 4;
                    v4f bb = *(const v4f*)(&bsrc[nb]);
                    float h0 = fast_tanh(acc[mt][0][0] + bb[0]);
                    float h1 = fast_tanh(acc[mt][0][1] + bb[1]);
                    float h2 = fast_tanh(acc[mt][0][2] + bb[2]);
                    float h3 = fast_tanh(acc[mt][0][3] + bb[3]);
                    float d0 = 1.0f - h0 * h0, d1 = 1.0f - h1 * h1;
                    float d2 = 1.0f - h2 * h2, d3 = 1.0f - h3 * h3;
                    uint2 w;
                    w.x = pk2(h0, h1); w.y = pk2(h2, h3);
                    *(uint2*)(&dst[l15 * LDW + nb]) = w;
                    #pragma unroll
                    for (int s = 1; s < 4; s++) {
                        w.x = pk2(d0 * acc[mt][s][0], d1 * acc[mt][s][1]);
                        w.y = pk2(d2 * acc[mt][s][2], d3 * acc[mt][s][3]);
                        *(uint2*)(&dst[(s * 16 + l15) * LDW + nb]) = w;
                    }
                }
            }
        }
        __syncthreads();   // B_b: XsC(i-1) ready

        // ---- phase 3: L4 (G3 waves, stream wvg, tile i-1) + cs prefetch (i+1) --
        if (g3 && i >= 1) {
            v4f a4 = {0.0f, 0.0f, 0.0f, 0.0f};
            #pragma unroll
            for (int kk = 0; kk < 8; kk++) {
                v8h A  = *(const v8h*)(&W4s[l15 * LDW + kk * 32 + q * 8]);
                v8h Bf = *(const v8h*)(&XsC[(wvg * 16 + l15) * LDW + kk * 32 + q * 8]);
                a4 = __builtin_amdgcn_mfma_f32_16x16x32_bf16(A, Bf, a4, 0, 0, 0);
            }
            if (q < 2) {
                #pragma unroll
                for (int r = 0; r < 4; r++)
                    Y4[wvg][l15][q * 4 + r] = a4[r];
            }
        }
        if (tid < TPTS * 3 && (i + 1) < nt_blk) {
            int p = tid / 3, c = tid % 3;
            int gp = base + GRIDB * TPTS + p; if (gp >= npts) gp = npts - 1;
            cs[tid] = coords[gp * 3 + c];
        }
        __syncthreads();   // B_c: Y4(i-1), cs(i+1) ready

        // ---- phase 4: residuals for tile i-1 (wave-0 threads 0..15) -----------
        if (i >= 1 && tid < 16) {
            const int pb = base - GRIDB * TPTS;    // tile (i-1) base
            if (pb + tid < npts) {
                const float* Yh = Y4[0][tid];
                const float* JX = Y4[1][tid];
                const float* JY = Y4[2][tid];
                const float* JT = Y4[3][tid];
                const float b40 = b4[0], b41 = b4[1], b42 = b4[2],
                            b43 = b4[3], b44 = b4[4], b45 = b4[5];
                const float wt0 = wts[0], wt1 = wts[1], wt2_ = wts[2], wt3_ = wts[3],
                            wt4_ = wts[4], wt5 = wts[5], wt6 = wts[6];
                const float g1 = 1.5f;
                float rho = Yh[0] + b40, vx = Yh[1] + b41, vy = Yh[2] + b42;
                float Bx  = Yh[3] + b43, By = Yh[4] + b44, P  = Yh[5] + b45;
                float v2 = vx * vx + vy * vy;
                float dt_rho = JT[0];
                float dt_rhovx = dt_rho * vx + rho * JT[1];
                float dt_rhovy = dt_rho * vy + rho * JT[2];
                auto dE = [&](const float* J) {
                    return J[5] * g1 + 0.5f * J[0] * v2 + rho * (vx * J[1] + vy * J[2]) + Bx * J[3] + By * J[4];
                };
                float dE_dx = dE(JX), dE_dy = dE(JY), dE_dt = dE(JT);
                float div_v = JX[1] + JY[2];
                float div_B = JX[3] + JY[4];
                float continuity = dt_rho + rho * div_v;
                float dPm_dx = JX[5] + Bx * JX[3] + By * JX[4];
                float dPm_dy = JY[5] + Bx * JY[3] + By * JY[4];
                float momentum_x = dt_rhovx + dPm_dx - (Bx * JX[3] + By * JY[3]);
                float momentum_y = dt_rhovy + dPm_dy - (Bx * JX[4] + By * JY[4]);
                auto dG = [&](const float* J) {
                    return J[1] * By + vx * J[4] - J[2] * Bx - vy * J[3];
                };
                float induction_x = JT[3] + dG(JY);
                float induction_y = JT[4] - dG(JX);
                float E = P * g1 + 0.5f * rho * v2 + 0.5f * (Bx * Bx + By * By);
                float S = E + P + 0.5f * (Bx * Bx + By * By);
                float dS_dx = dE_dx + JX[5] + Bx * JX[3] + By * JX[4];
                float dS_dy = dE_dy + JY[5] + Bx * JY[3] + By * JY[4];
                float D = Bx * vx + By * vy;
                auto dD = [&](const float* J) {
                    return J[3] * vx + Bx * J[1] + J[4] * vy + By * J[2];
                };
                float dFx_dx = dS_dx * vx + S * JX[1] - dD(JX) * Bx - D * JX[3];
                float dFy_dy = dS_dy * vy + S * JY[2] - dD(JY) * By - D * JY[4];
                float energy = dE_dt + dFx_dx + dFy_dy;
                vsum += wt0 * continuity * continuity
                      + wt1 * momentum_x * momentum_x
                      + wt2_ * momentum_y * momentum_y
                      + wt3_ * induction_x * induction_x
                      + wt4_ * induction_y * induction_y
                      + wt5 * energy * energy
                      + wt6 * div_B * div_B;
            }
        }
        // no extra barrier: next-iter B_a orders XsA/cs reuse; Y4 rewrite is 2 barriers away
    }

    if (tid < 64) {
        #pragma unroll
        for (int off = 8; off >= 1; off >>= 1)
            vsum += __shfl_down(vsum, off, 64);
        if (tid == 0) atomicAdd(out, vsum * inv_n);
    }
}

extern "C" void kernel_launch(void* const* d_in, const int* in_sizes, int n_in,
                              void* d_out, int out_size, void* d_ws, size_t ws_size,
                              hipStream_t stream) {
    const float* coords = (const float*)d_in[0];
    const float* W1 = (const float*)d_in[1];
    const float* b1 = (const float*)d_in[2];
    const float* W2 = (const float*)d_in[3];
    const float* b2 = (const float*)d_in[4];
    const float* W3 = (const float*)d_in[5];
    const float* b3 = (const float*)d_in[6];
    const float* W4 = (const float*)d_in[7];
    const float* b4 = (const float*)d_in[8];
    const float* wts = (const float*)d_in[9];
    const int npts = in_sizes[0] / 3;

    ushort* Wt2 = (ushort*)d_ws;
    ushort* Wt3 = Wt2 + 65536;
    ushort* Wt4 = Wt3 + 65536;

    hipMemsetAsync(d_out, 0, sizeof(float), stream);
    prep_weights<<<256, 256, 0, stream>>>(W2, W3, W4, Wt2, Wt3, Wt4);
    mhd_fused<<<GRIDB, 512, 0, stream>>>(coords, W1, b1, b2, b3, b4, wts,
                                         Wt2, Wt3, Wt4, (float*)d_out, npts, 1.0f / npts);
}

// Round 5
// 233.197 us; speedup vs baseline: 1.1127x; 1.1127x over previous
//
#include <hip/hip_runtime.h>
#include <hip/hip_bf16.h>
#include <cstdint>

// MHD PINN loss, fused + persistent, layer-pipelined wave specialization.
// N=131072 pts, H=256. Swapped-operand: D = W * X^T (m=neuron, n=16pts x 4 streams).
// Block = 512 thr (8 waves), grid = 256 (1 block/CU, 2 waves/SIMD).
// Waves 0-3 own L2 (64 neurons each, wf[4][8]=128 regs), waves 4-7 own L3.
// One-tile pipeline: G2 runs L2(tile i) while G3 runs L3(tile i-1), concurrently.
// Round-5 fixes vs Round 4 (which spilled: WRITE_SIZE 12.3 MB of scratch):
//  1. b4/wts hoisted out of loop (uniform -> SGPR; was ~7 MB of per-iter fetch).
//  2. b2/b3 biases staged in LDS (bias_s, 2 KB) -- no per-tile global loads, no regs.
//  3. Single live B-fragment (nt outer, mt inner): 4 live regs instead of 16.
// Streams: s=0 forward h, s=1..3 tangents d/dx,d/dy,d/dt; X row = s*16+p.

#define LDW 264   // X tile row stride in ushorts (132 words == 4 mod 32 -> 2-way max)
#define TPTS 16
#define GRIDB 256

typedef __attribute__((ext_vector_type(8))) short v8h;   // 8 x bf16
typedef __attribute__((ext_vector_type(4))) float v4f;

__device__ __forceinline__ ushort f2b(float f) {           // fp32 -> bf16 RNE
    uint32_t u = __float_as_uint(f);
    u = (u + 0x7fffu + ((u >> 16) & 1u)) >> 16;
    return (ushort)u;
}
__device__ __forceinline__ uint32_t pk2(float a, float b) { // packed cvt (v_cvt_pk_bf16_f32)
    union { __hip_bfloat162 h2; uint32_t u; } cv;
    cv.h2 = __float22bfloat162_rn(make_float2(a, b));
    return cv.u;
}
__device__ __forceinline__ float fast_tanh(float x) {
    float e = __expf(2.0f * x);
    return 1.0f - 2.0f * __builtin_amdgcn_rcpf(e + 1.0f);
}

// prep: W2,W3 (256x256 [k][n]) -> bf16 transposed Wt[n][k]; W4 (256x6) -> Wt4[16][256] padded
__global__ void prep_weights(const float* __restrict__ W2, const float* __restrict__ W3,
                             const float* __restrict__ W4,
                             ushort* __restrict__ Wt2, ushort* __restrict__ Wt3,
                             ushort* __restrict__ Wt4) {
    int idx = blockIdx.x * 256 + threadIdx.x;
    if (idx < 65536) {
        int k = idx >> 8, n = idx & 255;
        Wt2[n * 256 + k] = f2b(W2[k * 256 + n]);
        Wt3[n * 256 + k] = f2b(W3[k * 256 + n]);
    }
    if (idx < 4096) {
        int n = idx >> 8, k = idx & 255;
        Wt4[n * 256 + k] = (n < 6) ? f2b(W4[k * 6 + n]) : (ushort)0;
    }
}

__global__ __launch_bounds__(512, 2)
void mhd_fused(const float* __restrict__ coords,
               const float* __restrict__ W1, const float* __restrict__ b1,
               const float* __restrict__ b2, const float* __restrict__ b3,
               const float* __restrict__ b4,
               const float* __restrict__ wts,
               const ushort* __restrict__ Wt2, const ushort* __restrict__ Wt3,
               const ushort* __restrict__ Wt4,
               float* __restrict__ out, int npts, float inv_n) {
    __shared__ ushort XsA[64 * LDW];        // L1 output (single buffer)
    __shared__ ushort XsB[2][64 * LDW];     // L2 output (double buffer: pipeline cross-over)
    __shared__ ushort XsC[64 * LDW];        // L3 output (single buffer)
    __shared__ ushort W4s[16 * LDW];
    __shared__ float  bias_s[512];          // [0:256)=b2, [256:512)=b3
    __shared__ float  cs[TPTS * 3];
    __shared__ float  Y4[4][TPTS][8];

    const int tid  = threadIdx.x;
    const int lane = tid & 63;
    const int wv   = tid >> 6;      // 0..7
    const int q    = lane >> 4;
    const int l15  = lane & 15;
    const int g3   = wv >> 2;       // 0 = L2 group (waves 0-3), 1 = L3 group (waves 4-7)
    const int wvg  = wv & 3;        // index within group

    // ---- stage W4 (16x256, padded) + biases into LDS --------------------------
    for (int idx = tid; idx < 16 * 256; idx += 512)
        W4s[(idx >> 8) * LDW + (idx & 255)] = Wt4[idx];
    bias_s[tid] = (tid < 256) ? b2[tid] : b3[tid - 256];

    // ---- weight fragments -> registers: group owns one layer, 64 neurons/wave --
    const ushort* Wsrc = g3 ? Wt3 : Wt2;
    v8h wf[4][8];                                   // 128 regs
    #pragma unroll
    for (int mt = 0; mt < 4; mt++) {
        const int nrow = (wvg * 64 + mt * 16 + l15) * 256 + q * 8;
        #pragma unroll
        for (int kk = 0; kk < 8; kk++)
            wf[mt][kk] = *(const v8h*)(&Wsrc[nrow + kk * 32]);
    }

    const int jj = tid & 255, ph = tid >> 8;
    const float l1w0 = W1[jj], l1w1 = W1[256 + jj], l1w2 = W1[512 + jj], l1b = b1[jj];
    // uniform scalars (SGPR-resident) — hoisted: round 4 fetched these per tile
    const float b40 = b4[0], b41 = b4[1], b42 = b4[2], b43 = b4[3], b44 = b4[4], b45 = b4[5];
    const float wt0 = wts[0], wt1 = wts[1], wt2_ = wts[2], wt3_ = wts[3],
                wt4_ = wts[4], wt5 = wts[5], wt6 = wts[6];

    const int ntiles = (npts + TPTS - 1) / TPTS;
    const int nt_blk = (ntiles > (int)blockIdx.x)
                         ? (ntiles - (int)blockIdx.x + GRIDB - 1) / GRIDB : 0;

    float vsum = 0.0f;

    // prologue: coords for tile 0
    if (tid < TPTS * 3 && nt_blk > 0) {
        int p = tid / 3, c = tid % 3;
        int gp = (int)blockIdx.x * TPTS + p; if (gp >= npts) gp = npts - 1;
        cs[tid] = coords[gp * 3 + c];
    }
    __syncthreads();   // covers W4s, bias_s, cs(0)

    // pipeline: iteration i runs L1(i) | [L2(i) || L3(i-1)] | L4(i-1) | residual(i-1)
    for (int i = 0; i <= nt_blk; ++i) {
        const int base = ((int)blockIdx.x + i * GRIDB) * TPTS;

        // ---- phase 1: layer 1 (3->256) for tile i -> XsA ----------------------
        if (i < nt_blk) {
            #pragma unroll
            for (int pp = 0; pp < 8; pp++) {
                const int p = ph * 8 + pp;
                float x = cs[p * 3], y = cs[p * 3 + 1], t = cs[p * 3 + 2];
                float pre = fmaf(x, l1w0, fmaf(y, l1w1, fmaf(t, l1w2, l1b)));
                float h = fast_tanh(pre);
                float d = 1.0f - h * h;
                XsA[p * LDW + jj]        = f2b(h);
                XsA[(16 + p) * LDW + jj] = f2b(d * l1w0);
                XsA[(32 + p) * LDW + jj] = f2b(d * l1w1);
                XsA[(48 + p) * LDW + jj] = f2b(d * l1w2);
            }
        }
        __syncthreads();   // B_a: XsA(i) ready; XsB[i&1] free (G3 read it last iter)

        // ---- phase 2: G2 = L2(tile i): XsA -> XsB[i&1]
        //               G3 = L3(tile i-1): XsB[(i-1)&1] -> XsC  (concurrent) ------
        {
            const ushort* src = g3 ? XsB[(i + 1) & 1] : XsA;   // (i-1)&1 == (i+1)&1
            ushort*       dst = g3 ? XsC : XsB[i & 1];
            const bool act = g3 ? (i >= 1) : (i < nt_blk);
            if (act) {
                v4f acc[4][4];
                #pragma unroll
                for (int a = 0; a < 4; a++)
                    #pragma unroll
                    for (int b = 0; b < 4; b++) {
                        v4f z = {0.0f, 0.0f, 0.0f, 0.0f};
                        acc[a][b] = z;
                    }
                #pragma unroll
                for (int kk = 0; kk < 8; kk++) {
                    #pragma unroll
                    for (int nt = 0; nt < 4; nt++) {
                        v8h B = *(const v8h*)(&src[(nt * 16 + l15) * LDW + kk * 32 + q * 8]);
                        #pragma unroll
                        for (int mt = 0; mt < 4; mt++)
                            acc[mt][nt] = __builtin_amdgcn_mfma_f32_16x16x32_bf16(
                                              wf[mt][kk], B, acc[mt][nt], 0, 0, 0);
                    }
                }
                // D row(neuron) = mt*16 + q*4 + r, col = nt*16 + l15 (s = nt, p = l15)
                #pragma unroll
                for (int mt = 0; mt < 4; mt++) {
                    const int nb = wvg * 64 + mt * 16 + q * 4;
                    v4f bb = *(const v4f*)(&bias_s[g3 * 256 + nb]);
                    float h0 = fast_tanh(acc[mt][0][0] + bb[0]);
                    float h1 = fast_tanh(acc[mt][0][1] + bb[1]);
                    float h2 = fast_tanh(acc[mt][0][2] + bb[2]);
                    float h3 = fast_tanh(acc[mt][0][3] + bb[3]);
                    float d0 = 1.0f - h0 * h0, d1 = 1.0f - h1 * h1;
                    float d2 = 1.0f - h2 * h2, d3 = 1.0f - h3 * h3;
                    uint2 w;
                    w.x = pk2(h0, h1); w.y = pk2(h2, h3);
                    *(uint2*)(&dst[l15 * LDW + nb]) = w;
                    #pragma unroll
                    for (int s = 1; s < 4; s++) {
                        w.x = pk2(d0 * acc[mt][s][0], d1 * acc[mt][s][1]);
                        w.y = pk2(d2 * acc[mt][s][2], d3 * acc[mt][s][3]);
                        *(uint2*)(&dst[(s * 16 + l15) * LDW + nb]) = w;
                    }
                }
            }
        }
        __syncthreads();   // B_b: XsC(i-1) ready

        // ---- phase 3: L4 (G3 waves, stream wvg, tile i-1) + cs prefetch (i+1) --
        if (g3 && i >= 1) {
            v4f a4 = {0.0f, 0.0f, 0.0f, 0.0f};
            #pragma unroll
            for (int kk = 0; kk < 8; kk++) {
                v8h A  = *(const v8h*)(&W4s[l15 * LDW + kk * 32 + q * 8]);
                v8h Bf = *(const v8h*)(&XsC[(wvg * 16 + l15) * LDW + kk * 32 + q * 8]);
                a4 = __builtin_amdgcn_mfma_f32_16x16x32_bf16(A, Bf, a4, 0, 0, 0);
            }
            if (q < 2) {
                #pragma unroll
                for (int r = 0; r < 4; r++)
                    Y4[wvg][l15][q * 4 + r] = a4[r];
            }
        }
        if (tid < TPTS * 3 && (i + 1) < nt_blk) {
            int p = tid / 3, c = tid % 3;
            int gp = base + GRIDB * TPTS + p; if (gp >= npts) gp = npts - 1;
            cs[tid] = coords[gp * 3 + c];
        }
        __syncthreads();   // B_c: Y4(i-1), cs(i+1) ready

        // ---- phase 4: residuals for tile i-1 (wave-0 threads 0..15) -----------
        if (i >= 1 && tid < 16) {
            const int pb = base - GRIDB * TPTS;    // tile (i-1) base
            if (pb + tid < npts) {
                const float* Yh = Y4[0][tid];
                const float* JX = Y4[1][tid];
                const float* JY = Y4[2][tid];
                const float* JT = Y4[3][tid];
                const float g1 = 1.5f;
                float rho = Yh[0] + b40, vx = Yh[1] + b41, vy = Yh[2] + b42;
                float Bx  = Yh[3] + b43, By = Yh[4] + b44, P  = Yh[5] + b45;
                float v2 = vx * vx + vy * vy;
                float dt_rho = JT[0];
                float dt_rhovx = dt_rho * vx + rho * JT[1];
                float dt_rhovy = dt_rho * vy + rho * JT[2];
                auto dE = [&](const float* J) {
                    return J[5] * g1 + 0.5f * J[0] * v2 + rho * (vx * J[1] + vy * J[2]) + Bx * J[3] + By * J[4];
                };
                float dE_dx = dE(JX), dE_dy = dE(JY), dE_dt = dE(JT);
                float div_v = JX[1] + JY[2];
                float div_B = JX[3] + JY[4];
                float continuity = dt_rho + rho * div_v;
                float dPm_dx = JX[5] + Bx * JX[3] + By * JX[4];
                float dPm_dy = JY[5] + Bx * JY[3] + By * JY[4];
                float momentum_x = dt_rhovx + dPm_dx - (Bx * JX[3] + By * JY[3]);
                float momentum_y = dt_rhovy + dPm_dy - (Bx * JX[4] + By * JY[4]);
                auto dG = [&](const float* J) {
                    return J[1] * By + vx * J[4] - J[2] * Bx - vy * J[3];
                };
                float induction_x = JT[3] + dG(JY);
                float induction_y = JT[4] - dG(JX);
                float E = P * g1 + 0.5f * rho * v2 + 0.5f * (Bx * Bx + By * By);
                float S = E + P + 0.5f * (Bx * Bx + By * By);
                float dS_dx = dE_dx + JX[5] + Bx * JX[3] + By * JX[4];
                float dS_dy = dE_dy + JY[5] + Bx * JY[3] + By * JY[4];
                float D = Bx * vx + By * vy;
                auto dD = [&](const float* J) {
                    return J[3] * vx + Bx * J[1] + J[4] * vy + By * J[2];
                };
                float dFx_dx = dS_dx * vx + S * JX[1] - dD(JX) * Bx - D * JX[3];
                float dFy_dy = dS_dy * vy + S * JY[2] - dD(JY) * By - D * JY[4];
                float energy = dE_dt + dFx_dx + dFy_dy;
                vsum += wt0 * continuity * continuity
                      + wt1 * momentum_x * momentum_x
                      + wt2_ * momentum_y * momentum_y
                      + wt3_ * induction_x * induction_x
                      + wt4_ * induction_y * induction_y
                      + wt5 * energy * energy
                      + wt6 * div_B * div_B;
            }
        }
        // no extra barrier: next-iter B_a orders XsA/cs reuse; Y4 rewrite is 2 barriers away
    }

    if (tid < 64) {
        #pragma unroll
        for (int off = 8; off >= 1; off >>= 1)
            vsum += __shfl_down(vsum, off, 64);
        if (tid == 0) atomicAdd(out, vsum * inv_n);
    }
}

extern "C" void kernel_launch(void* const* d_in, const int* in_sizes, int n_in,
                              void* d_out, int out_size, void* d_ws, size_t ws_size,
                              hipStream_t stream) {
    const float* coords = (const float*)d_in[0];
    const float* W1 = (const float*)d_in[1];
    const float* b1 = (const float*)d_in[2];
    const float* W2 = (const float*)d_in[3];
    const float* b2 = (const float*)d_in[4];
    const float* W3 = (const float*)d_in[5];
    const float* b3 = (const float*)d_in[6];
    const float* W4 = (const float*)d_in[7];
    const float* b4 = (const float*)d_in[8];
    const float* wts = (const float*)d_in[9];
    const int npts = in_sizes[0] / 3;

    ushort* Wt2 = (ushort*)d_ws;
    ushort* Wt3 = Wt2 + 65536;
    ushort* Wt4 = Wt3 + 65536;

    hipMemsetAsync(d_out, 0, sizeof(float), stream);
    prep_weights<<<256, 256, 0, stream>>>(W2, W3, W4, Wt2, Wt3, Wt4);
    mhd_fused<<<GRIDB, 512, 0, stream>>>(coords, W1, b1, b2, b3, b4, wts,
                                         Wt2, Wt3, Wt4, (float*)d_out, npts, 1.0f / npts);
}